// Round 4
// baseline (184.451 us; speedup 1.0000x reference)
//
#include <hip/hip_runtime.h>
#include <math.h>

// Problem constants
#define B_ 4
#define CIN_ 32
#define COUT_ 64
#define H_ 32
#define W_ 32

// ws layout:
//   feat: float4[B*CIN*H*W]  (cos p, sin p, cos 3p, sin 3p)            = 2 MB
//   coef: float [g:16][c:32][kl:9][j:4][8]   (o = g*4+j; 8 = A1..4,B1..4)
#define FEAT_ELEMS (B_ * CIN_ * H_ * W_)      // 131072
#define COEF_OFF_BYTES (FEAT_ELEMS * 16)      // feat is float4
#define NCOEF (CIN_ * COUT_ * 9)              // 18432

__global__ __launch_bounds__(256) void ring_prep(
    const float* __restrict__ x, const float* __restrict__ probe,
    const float* __restrict__ outw, float* __restrict__ feat,
    float* __restrict__ coef) {
  int i = blockIdx.x * 256 + threadIdx.x;
  if (i < FEAT_ELEMS) {
    float p = x[i];
    float s1, c1;
    __sincosf(p, &s1, &c1);
    float c3 = c1 * fmaf(4.0f * c1, c1, -3.0f);
    float s3 = s1 * fmaf(-4.0f * s1, s1, 3.0f);
    float4 v;
    v.x = c1; v.y = s1; v.z = c3; v.w = s3;
    ((float4*)feat)[i] = v;
  }
  if (i < NCOEF) {
    // input flat idx: ((c*COUT + o)*3 + k)*3 + l
    int kl = i % 9;
    int co = i / 9;
    int o = co % COUT_;
    int c = co / COUT_;
    float th = probe[i];
    float wv = outw[i];
    float sth, cth, sw, cw;
    __sincosf(th, &sth, &cth);
    __sincosf(wv, &sw, &cw);
    float c3th = cth * fmaf(4.0f * cth, cth, -3.0f);
    float s3th = sth * fmaf(-4.0f * sth, sth, 3.0f);
    int g = o >> 2, j = o & 3;
    float* dst = coef + ((((size_t)g * CIN_ + c) * 9 + kl) * 4 + j) * 8;
    dst[0] = 0.75f * cw * cth;
    dst[1] = 0.75f * cw * sth;
    dst[2] = 0.25f * cw * c3th;
    dst[3] = 0.25f * cw * s3th;
    dst[4] = 0.75f * sw * cth;
    dst[5] = 0.75f * sw * sth;
    dst[6] = 0.25f * sw * c3th;
    dst[7] = 0.25f * sw * s3th;
  }
}

// Block: one (b,h) pixel row (32 px) x 32 outputs (8 quads). 256 threads:
// lane = (w, quad). Features via LDS (1 ds_read_b128/tap), coefficients via
// VMEM straight from L2 (590 KB array, L2-resident; lanes share addresses
// pairwise so each inst fetches 2x16B lines). Grid = 256 blocks -> 1/CU.
#define LDSW 34

__global__ __launch_bounds__(256) void ring_main(
    const float4* __restrict__ feat, const float* __restrict__ coef,
    float* __restrict__ out) {
  __shared__ float4 sfeat[3 * CIN_ * LDSW];   // [k:3][c:32][wcol:34]

  int blk = blockIdx.x;          // ((b*32 + h)*2 + oh)
  int oh = blk & 1;
  int h = (blk >> 1) & 31;
  int b = blk >> 6;
  int tid = threadIdx.x;
  int w = tid & 31;
  int q = tid >> 5;              // 0..7
  int og = oh * 8 + q;           // output quad 0..15 (o = og*4 + j)

  // ---- stage 3 padded feature rows into LDS ----
  for (int e = tid; e < 3 * CIN_ * LDSW; e += 256) {
    int r = e / (CIN_ * LDSW);
    int rem = e - r * (CIN_ * LDSW);
    int c = rem / LDSW;
    int wc = rem - c * LDSW;
    int hs = h - 1 + r;
    int ws = wc - 1;
    float4 v = make_float4(1.0f, 0.0f, 1.0f, 0.0f);  // p = 0 pad
    if ((unsigned)hs < (unsigned)H_ && (unsigned)ws < (unsigned)W_)
      v = feat[((b * CIN_ + c) * H_ + hs) * W_ + ws];
    sfeat[e] = v;
  }
  __syncthreads();

  const float4* cbase = (const float4*)(coef + (size_t)og * (CIN_ * 9 * 32));

  float ax0 = 0.f, ax1 = 0.f, ax2 = 0.f, ax3 = 0.f;
  float ay0 = 0.f, ay1 = 0.f, ay2 = 0.f, ay3 = 0.f;

  for (int c = 0; c < CIN_; ++c) {
#pragma unroll
    for (int k = 0; k < 3; ++k) {
#pragma unroll
      for (int l = 0; l < 3; ++l) {
        int kl = k * 3 + l;
        float4 f = sfeat[(k * CIN_ + c) * LDSW + w + l];
        const float4* cp = cbase + (size_t)(c * 9 + kl) * 8;  // [j:4][A4,B4]
        float4 a0 = cp[0], b0 = cp[1], a1 = cp[2], b1 = cp[3];
        float4 a2 = cp[4], b2 = cp[5], a3 = cp[6], b3 = cp[7];
        ax0 = fmaf(a0.x, f.x, ax0); ax0 = fmaf(a0.y, f.y, ax0);
        ax0 = fmaf(a0.z, f.z, ax0); ax0 = fmaf(a0.w, f.w, ax0);
        ay0 = fmaf(b0.x, f.x, ay0); ay0 = fmaf(b0.y, f.y, ay0);
        ay0 = fmaf(b0.z, f.z, ay0); ay0 = fmaf(b0.w, f.w, ay0);
        ax1 = fmaf(a1.x, f.x, ax1); ax1 = fmaf(a1.y, f.y, ax1);
        ax1 = fmaf(a1.z, f.z, ax1); ax1 = fmaf(a1.w, f.w, ax1);
        ay1 = fmaf(b1.x, f.x, ay1); ay1 = fmaf(b1.y, f.y, ay1);
        ay1 = fmaf(b1.z, f.z, ay1); ay1 = fmaf(b1.w, f.w, ay1);
        ax2 = fmaf(a2.x, f.x, ax2); ax2 = fmaf(a2.y, f.y, ax2);
        ax2 = fmaf(a2.z, f.z, ax2); ax2 = fmaf(a2.w, f.w, ax2);
        ay2 = fmaf(b2.x, f.x, ay2); ay2 = fmaf(b2.y, f.y, ay2);
        ay2 = fmaf(b2.z, f.z, ay2); ay2 = fmaf(b2.w, f.w, ay2);
        ax3 = fmaf(a3.x, f.x, ax3); ax3 = fmaf(a3.y, f.y, ax3);
        ax3 = fmaf(a3.z, f.z, ax3); ax3 = fmaf(a3.w, f.w, ax3);
        ay3 = fmaf(b3.x, f.x, ay3); ay3 = fmaf(b3.y, f.y, ay3);
        ay3 = fmaf(b3.z, f.z, ay3); ay3 = fmaf(b3.w, f.w, ay3);
      }
    }
  }

  int o = og * 4;
  out[((b * COUT_ + o + 0) * H_ + h) * W_ + w] = atan2f(ay0, ax0);
  out[((b * COUT_ + o + 1) * H_ + h) * W_ + w] = atan2f(ay1, ax1);
  out[((b * COUT_ + o + 2) * H_ + h) * W_ + w] = atan2f(ay2, ax2);
  out[((b * COUT_ + o + 3) * H_ + h) * W_ + w] = atan2f(ay3, ax3);
}

extern "C" void kernel_launch(void* const* d_in, const int* in_sizes, int n_in,
                              void* d_out, int out_size, void* d_ws, size_t ws_size,
                              hipStream_t stream) {
  const float* x = (const float*)d_in[0];
  const float* probe = (const float*)d_in[1];
  const float* outw = (const float*)d_in[2];
  float* feat = (float*)d_ws;
  float* coef = (float*)((char*)d_ws + COEF_OFF_BYTES);
  float* out = (float*)d_out;

  ring_prep<<<FEAT_ELEMS / 256, 256, 0, stream>>>(x, probe, outw, feat, coef);
  ring_main<<<B_ * H_ * 2, 256, 0, stream>>>((const float4*)feat, coef, out);
}

// Round 6
// 80.843 us; speedup vs baseline: 2.2816x; 2.2816x over previous
//
#include <hip/hip_runtime.h>
#include <math.h>

// Problem constants
#define B_ 4
#define CIN_ 32
#define COUT_ 64
#define H_ 32
#define W_ 32

typedef _Float16 half8 __attribute__((ext_vector_type(8)));
typedef float floatx4 __attribute__((ext_vector_type(4)));

// ---------------- workspace layout ----------------
// feat_f16: [var 2][b 4][row 34][col 34][chunk p 16][16B]  (fp16, chunk-swizzled)
//   row = h+1 (h in -1..32), col = w+1 (w in -1..32); pad taps = (1,0,1,0)
//   position p holds k-chunk q = p ^ (col & 7); k = q*8+j, c = k>>2, feat = k&3
// B_f16:   [var 2][tap 9][n 128][chunk p 16][16B]
//   n = xy*64 + o; position p holds chunk q = p ^ (n & 7)
// var 0 = hi, var 1 = lo*2048
#define FEAT_BYTES (2u * 4 * 34 * 34 * 256)   // 2,367,488
#define NFEAT_THR (4 * 34 * 34 * 16)          // 73984
#define NB_THR (9 * 128 * 16)                 // 18432

__global__ __launch_bounds__(256) void ring_prep(
    const float* __restrict__ x, const float* __restrict__ probe,
    const float* __restrict__ outw, char* __restrict__ ws) {
  int i = blockIdx.x * 256 + threadIdx.x;
  if (i < NFEAT_THR) {
    int p = i & 15;
    int t = i >> 4;
    int col = t % 34;
    t /= 34;
    int row = t % 34;
    int b = t / 34;
    int qd = p ^ (col & 7);
    int h = row - 1, w = col - 1;
    bool valid = (unsigned)h < 32u && (unsigned)w < 32u;
    half8 hi, lo;
#pragma unroll
    for (int half = 0; half < 2; ++half) {
      int c = qd * 2 + half;
      float c1 = 1.0f, s1 = 0.0f;
      if (valid) {
        float pv = x[((b * 32 + c) * 32 + h) * 32 + w];
        __sincosf(pv, &s1, &c1);
      }
      float c3 = c1 * fmaf(4.0f * c1, c1, -3.0f);
      float s3 = s1 * fmaf(-4.0f * s1, s1, 3.0f);
      float v4[4] = {c1, s1, c3, s3};
#pragma unroll
      for (int f = 0; f < 4; ++f) {
        _Float16 hv = (_Float16)v4[f];
        hi[half * 4 + f] = hv;
        lo[half * 4 + f] = (_Float16)((v4[f] - (float)hv) * 2048.0f);
      }
    }
    size_t off = (((size_t)(0 * 4 + b) * 34 + row) * 34 + col) * 256 + p * 16;
    size_t vstride = (size_t)4 * 34 * 34 * 256;
    *(half8*)(ws + off) = hi;
    *(half8*)(ws + off + vstride) = lo;
  } else if (i < NFEAT_THR + NB_THR) {
    int j = i - NFEAT_THR;
    int p = j & 15;
    int n = (j >> 4) & 127;
    int tap = j >> 11;
    int qd = p ^ (n & 7);
    int o = n & 63;
    int xy = n >> 6;
    half8 hi, lo;
#pragma unroll
    for (int half = 0; half < 2; ++half) {
      int c = qd * 2 + half;
      int idx = (c * 64 + o) * 9 + tap;
      float th = probe[idx];
      float wvv = outw[idx];
      float sth, cth, sw, cw;
      __sincosf(th, &sth, &cth);
      __sincosf(wvv, &sw, &cw);
      float c3 = cth * fmaf(4.0f * cth, cth, -3.0f);
      float s3 = sth * fmaf(-4.0f * sth, sth, 3.0f);
      float m = xy ? sw : cw;
      float v4[4] = {0.75f * m * cth, 0.75f * m * sth, 0.25f * m * c3,
                     0.25f * m * s3};
#pragma unroll
      for (int f = 0; f < 4; ++f) {
        _Float16 hv = (_Float16)v4[f];
        hi[half * 4 + f] = hv;
        lo[half * 4 + f] = (_Float16)((v4[f] - (float)hv) * 2048.0f);
      }
    }
    size_t off = FEAT_BYTES + (((size_t)(0 * 9 + tap) * 128 + n) * 256 + p * 16);
    size_t vstride = (size_t)9 * 128 * 256;
    *(half8*)(ws + off) = hi;
    *(half8*)(ws + off + vstride) = lo;
  }
}

// Block: 16 px (row h, w = wt*16..+15) x 64 n ({oh*32..+31} u {64+oh*32..+31}).
// 4 waves; wave wv: xy = wv>>1, og = wv&1 -> one 16x16 n-frag, one 16-px m-frag.
// A-tile (3 rows x 18 cols x 128k x 2 var fp16 = 27.6 KB) staged once;
// B per tap (64 n x 128 k x 2 var = 32 KB) staged per iteration.
__global__ __launch_bounds__(256) void ring_mfma(
    const char* __restrict__ featg, const char* __restrict__ Bg,
    float* __restrict__ out) {
  __shared__ __align__(16) char sA[27648];
  __shared__ __align__(16) char sB[32768];
  __shared__ float sEx[512];  // [og 2][n 16][m 16]

  int blk = blockIdx.x;  // ((b*32 + h)*2 + wt)*2 + oh
  int oh = blk & 1;
  int wt = (blk >> 1) & 1;
  int h = (blk >> 2) & 31;
  int b = blk >> 7;
  int tid = threadIdx.x;

  // ---- stage A tile: 1728 x 16B units, layout [var][r 3][colidx 18][256B] ----
  for (int u = tid; u < 1728; u += 256) {
    int v = u / 864;
    int r = (u - v * 864) / 288;
    int rest = u % 288;  // 18 cols x 256 B
    size_t goff = (size_t)v * (4u * 34 * 34 * 256) +
                  (((size_t)b * 34 + (h + r)) * 34 + wt * 16) * 256 + rest * 16;
    *(float4*)(sA + u * 16) = *(const float4*)(featg + goff);
  }

  int lane = tid & 63;
  int wv = tid >> 6;
  int n16 = lane & 15;
  int quad = lane >> 4;
  int xy = wv >> 1;
  int og = wv & 1;

  floatx4 acc0 = {0.f, 0.f, 0.f, 0.f};
  floatx4 acc1 = {0.f, 0.f, 0.f, 0.f};

  int nloc = xy * 32 + og * 16 + n16;  // row within sB (per var)
  int bkey = lane & 7;

  for (int tap = 0; tap < 9; ++tap) {
    __syncthreads();  // prior compute done (also orders A staging on tap 0)
    // ---- stage B chunk: 2048 x 16B units, layout [var][64 n][256B] ----
    // NOTE: Bg already points at the B array (ws + FEAT_BYTES) — do NOT
    // add FEAT_BYTES here (round-5 bug: double offset read poison).
    for (int u = tid; u < 2048; u += 256) {
      int v = u >> 10;
      int seg = (u >> 9) & 1;
      int within = u & 511;  // 32 rows x 256 B
      size_t goff = (size_t)v * (9u * 128 * 256) +
                    ((size_t)tap * 128 + seg * 64 + oh * 32) * 256 + within * 16;
      *(float4*)(sB + u * 16) = *(const float4*)(Bg + goff);
    }
    __syncthreads();

    int dk = tap / 3;
    int l = tap - dk * 3;
    int colidx = n16 + l;  // m + l; m = lane&15 (pixel index)
    int akey = colidx & 7;
    const char* aH = sA + (dk * 18 + colidx) * 256;
    const char* aL = sA + ((3 + dk) * 18 + colidx) * 256;
    const char* bH = sB + nloc * 256;
    const char* bL = sB + 16384 + nloc * 256;

#pragma unroll
    for (int ks = 0; ks < 4; ++ks) {
      int q = ks * 4 + quad;
      int pa = (q ^ akey) * 16;
      int pb = (q ^ bkey) * 16;
      half8 Ah = *(const half8*)(aH + pa);
      half8 Al = *(const half8*)(aL + pa);
      half8 Bh = *(const half8*)(bH + pb);
      half8 Bl = *(const half8*)(bL + pb);
      acc0 = __builtin_amdgcn_mfma_f32_16x16x32_f16(Ah, Bh, acc0, 0, 0, 0);
      acc1 = __builtin_amdgcn_mfma_f32_16x16x32_f16(Al, Bh, acc1, 0, 0, 0);
      acc1 = __builtin_amdgcn_mfma_f32_16x16x32_f16(Ah, Bl, acc1, 0, 0, 0);
    }
  }

  floatx4 fin = acc0 + acc1 * (1.0f / 2048.0f);

  // ---- epilogue: y-waves hand ay to x-waves; x-waves atan2 + store ----
  __syncthreads();
  if (xy == 1) {
#pragma unroll
    for (int r = 0; r < 4; ++r)
      sEx[(og * 16 + n16) * 16 + quad * 4 + r] = fin[r];
  }
  __syncthreads();
  if (xy == 0) {
    int o = oh * 32 + og * 16 + n16;
    float4 res;
    float* rp = (float*)&res;
#pragma unroll
    for (int r = 0; r < 4; ++r) {
      int m = quad * 4 + r;
      float ay = sEx[(og * 16 + n16) * 16 + m];
      rp[r] = atan2f(ay, fin[r]);
    }
    float* dst = out + (((size_t)(b * 64 + o) * 32 + h) * 32 + wt * 16 + quad * 4);
    *(float4*)dst = res;
  }
}

extern "C" void kernel_launch(void* const* d_in, const int* in_sizes, int n_in,
                              void* d_out, int out_size, void* d_ws, size_t ws_size,
                              hipStream_t stream) {
  const float* x = (const float*)d_in[0];
  const float* probe = (const float*)d_in[1];
  const float* outw = (const float*)d_in[2];
  char* ws = (char*)d_ws;
  float* out = (float*)d_out;

  int prep_threads = NFEAT_THR + NB_THR;  // 92416 = 361 * 256
  ring_prep<<<(prep_threads + 255) / 256, 256, 0, stream>>>(x, probe, outw, ws);
  ring_mfma<<<512, 256, 0, stream>>>(ws, ws + FEAT_BYTES, out);
}

// Round 7
// 73.835 us; speedup vs baseline: 2.4982x; 1.0949x over previous
//
#include <hip/hip_runtime.h>
#include <math.h>

// Problem constants
#define B_ 4
#define CIN_ 32
#define COUT_ 64
#define H_ 32
#define W_ 32

typedef _Float16 half8 __attribute__((ext_vector_type(8)));
typedef float floatx4 __attribute__((ext_vector_type(4)));

// ---------------- workspace layout ----------------
// feat_f16: [var 2][b 4][row 34][col 34][chunk p 16][16B]  (fp16, chunk-swizzled)
//   row = h+1 (h in -1..32), col = w+1 (w in -1..32); pad taps = (1,0,1,0)
//   position p holds k-chunk q = p ^ (col & 7); k = q*8+j, c = k>>2, feat = k&3
// B_f16:   [var 2][tap 9][n 128][chunk p 16][16B]
//   n = xy*64 + o; position p holds chunk q = p ^ (n & 7)
// var 0 = hi, var 1 = lo*2048
#define FEAT_BYTES (2u * 4 * 34 * 34 * 256)   // 2,367,488
#define NFEAT_THR (4 * 34 * 34 * 16)          // 73984
#define NB_THR (9 * 128 * 16)                 // 18432

__global__ __launch_bounds__(256) void ring_prep(
    const float* __restrict__ x, const float* __restrict__ probe,
    const float* __restrict__ outw, char* __restrict__ ws) {
  int i = blockIdx.x * 256 + threadIdx.x;
  if (i < NFEAT_THR) {
    int p = i & 15;
    int t = i >> 4;
    int col = t % 34;
    t /= 34;
    int row = t % 34;
    int b = t / 34;
    int qd = p ^ (col & 7);
    int h = row - 1, w = col - 1;
    bool valid = (unsigned)h < 32u && (unsigned)w < 32u;
    half8 hi, lo;
#pragma unroll
    for (int half = 0; half < 2; ++half) {
      int c = qd * 2 + half;
      float c1 = 1.0f, s1 = 0.0f;
      if (valid) {
        float pv = x[((b * 32 + c) * 32 + h) * 32 + w];
        __sincosf(pv, &s1, &c1);
      }
      float c3 = c1 * fmaf(4.0f * c1, c1, -3.0f);
      float s3 = s1 * fmaf(-4.0f * s1, s1, 3.0f);
      float v4[4] = {c1, s1, c3, s3};
#pragma unroll
      for (int f = 0; f < 4; ++f) {
        _Float16 hv = (_Float16)v4[f];
        hi[half * 4 + f] = hv;
        lo[half * 4 + f] = (_Float16)((v4[f] - (float)hv) * 2048.0f);
      }
    }
    size_t off = (((size_t)(0 * 4 + b) * 34 + row) * 34 + col) * 256 + p * 16;
    size_t vstride = (size_t)4 * 34 * 34 * 256;
    *(half8*)(ws + off) = hi;
    *(half8*)(ws + off + vstride) = lo;
  } else if (i < NFEAT_THR + NB_THR) {
    int j = i - NFEAT_THR;
    int p = j & 15;
    int n = (j >> 4) & 127;
    int tap = j >> 11;
    int qd = p ^ (n & 7);
    int o = n & 63;
    int xy = n >> 6;
    half8 hi, lo;
#pragma unroll
    for (int half = 0; half < 2; ++half) {
      int c = qd * 2 + half;
      int idx = (c * 64 + o) * 9 + tap;
      float th = probe[idx];
      float wvv = outw[idx];
      float sth, cth, sw, cw;
      __sincosf(th, &sth, &cth);
      __sincosf(wvv, &sw, &cw);
      float c3 = cth * fmaf(4.0f * cth, cth, -3.0f);
      float s3 = sth * fmaf(-4.0f * sth, sth, 3.0f);
      float m = xy ? sw : cw;
      float v4[4] = {0.75f * m * cth, 0.75f * m * sth, 0.25f * m * c3,
                     0.25f * m * s3};
#pragma unroll
      for (int f = 0; f < 4; ++f) {
        _Float16 hv = (_Float16)v4[f];
        hi[half * 4 + f] = hv;
        lo[half * 4 + f] = (_Float16)((v4[f] - (float)hv) * 2048.0f);
      }
    }
    size_t off = FEAT_BYTES + (((size_t)(0 * 9 + tap) * 128 + n) * 256 + p * 16);
    size_t vstride = (size_t)9 * 128 * 256;
    *(half8*)(ws + off) = hi;
    *(half8*)(ws + off + vstride) = lo;
  }
}

// Block: 16 px (row h, w = wt*16..+15) x 64 n ({oh*32..+31} u {64+oh*32..+31}).
// 4 waves; wave wv: xy = wv>>1, og = wv&1 -> one 16x16 n-frag, one 16-px m-frag.
// A-tile (3 rows x 18 cols x 128k x 2 var fp16 = 27.6 KB) staged once in LDS.
// B fragments read DIRECTLY from global (590 KB, L2-resident): each load is
// 64 lanes x 16 B = 1 KB, no LDS staging, no per-tap barriers -> the 9-tap
// loop is straight-line and the compiler pipelines loads with vmcnt.
__global__ __launch_bounds__(256, 2) void ring_mfma(
    const char* __restrict__ featg, const char* __restrict__ Bg,
    float* __restrict__ out) {
  __shared__ __align__(16) char sA[27648];
  __shared__ float sEx[512];  // [og 2][n 16][m 16]

  int blk = blockIdx.x;  // ((b*32 + h)*2 + wt)*2 + oh
  int oh = blk & 1;
  int wt = (blk >> 1) & 1;
  int h = (blk >> 2) & 31;
  int b = blk >> 7;
  int tid = threadIdx.x;

  // ---- stage A tile: 1728 x 16B units, layout [var][r 3][colidx 18][256B] ----
  for (int u = tid; u < 1728; u += 256) {
    int v = u / 864;
    int r = (u - v * 864) / 288;
    int rest = u % 288;  // 18 cols x 256 B
    size_t goff = (size_t)v * (4u * 34 * 34 * 256) +
                  (((size_t)b * 34 + (h + r)) * 34 + wt * 16) * 256 + rest * 16;
    *(float4*)(sA + u * 16) = *(const float4*)(featg + goff);
  }

  int lane = tid & 63;
  int wv = tid >> 6;
  int n16 = lane & 15;
  int quad = lane >> 4;
  int xy = wv >> 1;
  int og = wv & 1;

  floatx4 acc0 = {0.f, 0.f, 0.f, 0.f};
  floatx4 acc1 = {0.f, 0.f, 0.f, 0.f};

  // global n this lane's B column lives at; swizzle key n&7 == n16&7 since
  // xy*64, oh*32, og*16 are all 0 mod 8.
  int n_global = xy * 64 + oh * 32 + og * 16 + n16;
  const char* bRow = Bg + (size_t)n_global * 256;
  int bkey = n16 & 7;

  __syncthreads();  // A tile visible; tap loop is barrier-free

#pragma unroll
  for (int tap = 0; tap < 9; ++tap) {
    int dk = tap / 3;
    int l = tap - dk * 3;
    int colidx = n16 + l;  // m + l; m = lane&15 (pixel index)
    int akey = colidx & 7;
    const char* aH = sA + (dk * 18 + colidx) * 256;
    const char* aL = sA + ((3 + dk) * 18 + colidx) * 256;
    const char* bH = bRow + (size_t)tap * (128 * 256);
    const char* bL = bH + (size_t)9 * 128 * 256;

#pragma unroll
    for (int ks = 0; ks < 4; ++ks) {
      int q = ks * 4 + quad;
      int pa = (q ^ akey) * 16;
      int pb = (q ^ bkey) * 16;
      half8 Ah = *(const half8*)(aH + pa);
      half8 Al = *(const half8*)(aL + pa);
      half8 Bh = *(const half8*)(bH + pb);
      half8 Bl = *(const half8*)(bL + pb);
      acc0 = __builtin_amdgcn_mfma_f32_16x16x32_f16(Ah, Bh, acc0, 0, 0, 0);
      acc1 = __builtin_amdgcn_mfma_f32_16x16x32_f16(Al, Bh, acc1, 0, 0, 0);
      acc1 = __builtin_amdgcn_mfma_f32_16x16x32_f16(Ah, Bl, acc1, 0, 0, 0);
    }
  }

  floatx4 fin = acc0 + acc1 * (1.0f / 2048.0f);

  // ---- epilogue: y-waves hand ay to x-waves; x-waves atan2 + store ----
  __syncthreads();
  if (xy == 1) {
#pragma unroll
    for (int r = 0; r < 4; ++r)
      sEx[(og * 16 + n16) * 16 + quad * 4 + r] = fin[r];
  }
  __syncthreads();
  if (xy == 0) {
    int o = oh * 32 + og * 16 + n16;
    float4 res;
    float* rp = (float*)&res;
#pragma unroll
    for (int r = 0; r < 4; ++r) {
      int m = quad * 4 + r;
      float ay = sEx[(og * 16 + n16) * 16 + m];
      rp[r] = atan2f(ay, fin[r]);
    }
    float* dst = out + (((size_t)(b * 64 + o) * 32 + h) * 32 + wt * 16 + quad * 4);
    *(float4*)dst = res;
  }
}

extern "C" void kernel_launch(void* const* d_in, const int* in_sizes, int n_in,
                              void* d_out, int out_size, void* d_ws, size_t ws_size,
                              hipStream_t stream) {
  const float* x = (const float*)d_in[0];
  const float* probe = (const float*)d_in[1];
  const float* outw = (const float*)d_in[2];
  char* ws = (char*)d_ws;
  float* out = (float*)d_out;

  int prep_threads = NFEAT_THR + NB_THR;  // 92416 = 361 * 256
  ring_prep<<<(prep_threads + 255) / 256, 256, 0, stream>>>(x, probe, outw, ws);
  ring_mfma<<<512, 256, 0, stream>>>(ws, ws + FEAT_BYTES, out);
}

// Round 8
// 71.212 us; speedup vs baseline: 2.5902x; 1.0368x over previous
//
#include <hip/hip_runtime.h>
#include <math.h>

// Problem constants: B=4, CIN=32, COUT=64, H=W=32, K=3, pad=1

typedef _Float16 half8 __attribute__((ext_vector_type(8)));
typedef float floatx4 __attribute__((ext_vector_type(4)));

// ---------------- workspace layout (B only; feat array is gone) ----------
// B_f16: [var 2][tap 9][n 128][chunk p 16][16B]
//   n = xy*64 + o (xy: 0=cos-weights, 1=sin-weights); position p holds
//   k-chunk q = p ^ (n & 7); k = q*8 + j, c = k>>2, feat = k&3
//   var 0 = hi, var 1 = lo*2048      total 2 x 294912 B = 576 KB (L2-resident)
#define B_VSTRIDE (9u * 128 * 256)   // 294912

__global__ __launch_bounds__(256) void ring_prep_b(
    const float* __restrict__ probe, const float* __restrict__ outw,
    char* __restrict__ Bg) {
  int i = blockIdx.x * 256 + threadIdx.x;   // 18432 threads = 72 blocks
  int p = i & 15;
  int n = (i >> 4) & 127;
  int tap = i >> 11;
  int qd = p ^ (n & 7);
  int o = n & 63;
  int xy = n >> 6;
  half8 hi, lo;
#pragma unroll
  for (int hf = 0; hf < 2; ++hf) {
    int c = qd * 2 + hf;
    int idx = (c * 64 + o) * 9 + tap;       // ((c*COUT + o)*3 + k)*3 + l
    float th = probe[idx];
    float wvv = outw[idx];
    float sth, cth, sw, cw;
    __sincosf(th, &sth, &cth);
    __sincosf(wvv, &sw, &cw);
    float c3 = cth * fmaf(4.0f * cth, cth, -3.0f);
    float s3 = sth * fmaf(-4.0f * sth, sth, 3.0f);
    float m = xy ? sw : cw;
    float v4[4] = {0.75f * m * cth, 0.75f * m * sth, 0.25f * m * c3,
                   0.25f * m * s3};
#pragma unroll
    for (int f = 0; f < 4; ++f) {
      _Float16 hv = (_Float16)v4[f];
      hi[hf * 4 + f] = hv;
      lo[hf * 4 + f] = (_Float16)((v4[f] - (float)hv) * 2048.0f);
    }
  }
  size_t off = (((size_t)tap * 128 + n) * 16 + p) * 16;
  *(half8*)(Bg + off) = hi;
  *(half8*)(Bg + off + B_VSTRIDE) = lo;
}

// Block: 16 px (row h, w = wt*16..+15) x 64 n ({oh*32..+31} u {64+oh*32..+31}).
// 4 waves; wave wv: xy = wv>>1, og = wv&1 -> one 16x16 n-frag, one 16-px m-frag.
// A-tile features (cos p, sin p, cos 3p, sin 3p as fp16 hi/lo) are computed
// IN-BLOCK from x (6.9 KB unique) straight into swizzled LDS — no feat array.
// sA layout: [var 2][r 3][colidx 18][p 16][16B]; chunk q = p ^ (colidx & 7).
// B fragments read directly from global (L2-resident), no per-tap barriers.
__global__ __launch_bounds__(256, 2) void ring_mfma(
    const float* __restrict__ x, const char* __restrict__ Bg,
    float* __restrict__ out) {
  __shared__ __align__(16) char sA[27648];
  __shared__ float sEx[512];  // [og 2][n 16][m 16]

  int blk = blockIdx.x;  // ((b*32 + h)*2 + wt)*2 + oh
  int oh = blk & 1;
  int wt = (blk >> 1) & 1;
  int h = (blk >> 2) & 31;
  int b = blk >> 7;
  int tid = threadIdx.x;

  // ---- compute A tile in-block: 864 hi/lo unit pairs ----
  for (int u = tid; u < 864; u += 256) {
    int r = u / 288;
    int t = u - r * 288;
    int colidx = t >> 4;
    int p = t & 15;
    int q = p ^ (colidx & 7);
    int hs = h + r - 1;
    int wsx = wt * 16 + colidx - 1;
    bool valid = ((unsigned)hs < 32u) && ((unsigned)wsx < 32u);
    half8 hi, lo;
#pragma unroll
    for (int hf = 0; hf < 2; ++hf) {
      int c = q * 2 + hf;
      float c1 = 1.0f, s1 = 0.0f;
      if (valid) {
        float pv = x[((b * 32 + c) * 32 + hs) * 32 + wsx];
        __sincosf(pv, &s1, &c1);
      }
      float c3 = c1 * fmaf(4.0f * c1, c1, -3.0f);
      float s3 = s1 * fmaf(-4.0f * s1, s1, 3.0f);
      float v4[4] = {c1, s1, c3, s3};
#pragma unroll
      for (int f = 0; f < 4; ++f) {
        _Float16 hv = (_Float16)v4[f];
        hi[hf * 4 + f] = hv;
        lo[hf * 4 + f] = (_Float16)((v4[f] - (float)hv) * 2048.0f);
      }
    }
    *(half8*)(sA + u * 16) = hi;            // var 0 section
    *(half8*)(sA + u * 16 + 13824) = lo;    // var 1 section (864*16)
  }

  int lane = tid & 63;
  int wv = tid >> 6;
  int n16 = lane & 15;
  int quad = lane >> 4;
  int xy = wv >> 1;
  int og = wv & 1;

  floatx4 acc0 = {0.f, 0.f, 0.f, 0.f};   // Ah*Bh
  floatx4 acc1 = {0.f, 0.f, 0.f, 0.f};   // Al*Bh
  floatx4 acc2 = {0.f, 0.f, 0.f, 0.f};   // Ah*Bl

  // global n this lane's B column lives at; swizzle key n&7 == n16&7 since
  // xy*64, oh*32, og*16 are all 0 mod 8.
  int n_global = xy * 64 + oh * 32 + og * 16 + n16;
  const char* bRow = Bg + (size_t)n_global * 256;
  int bkey = n16 & 7;

  __syncthreads();  // A tile visible; tap loop is barrier-free

#pragma unroll
  for (int tap = 0; tap < 9; ++tap) {
    int dk = tap / 3;
    int l = tap - dk * 3;
    int colidx = n16 + l;  // m + l; m = lane&15 (pixel index)
    int akey = colidx & 7;
    const char* aH = sA + (dk * 18 + colidx) * 256;
    const char* aL = sA + ((3 + dk) * 18 + colidx) * 256;
    const char* bH = bRow + (size_t)tap * (128 * 256);
    const char* bL = bH + B_VSTRIDE;

#pragma unroll
    for (int ks = 0; ks < 4; ++ks) {
      int q = ks * 4 + quad;
      int pa = (q ^ akey) * 16;
      int pb = (q ^ bkey) * 16;
      half8 Ah = *(const half8*)(aH + pa);
      half8 Al = *(const half8*)(aL + pa);
      half8 Bh = *(const half8*)(bH + pb);
      half8 Bl = *(const half8*)(bL + pb);
      acc0 = __builtin_amdgcn_mfma_f32_16x16x32_f16(Ah, Bh, acc0, 0, 0, 0);
      acc1 = __builtin_amdgcn_mfma_f32_16x16x32_f16(Al, Bh, acc1, 0, 0, 0);
      acc2 = __builtin_amdgcn_mfma_f32_16x16x32_f16(Ah, Bl, acc2, 0, 0, 0);
    }
  }

  floatx4 fin = acc0 + (acc1 + acc2) * (1.0f / 2048.0f);

  // ---- epilogue: y-waves hand ay to x-waves; x-waves atan2 + store ----
  __syncthreads();
  if (xy == 1) {
#pragma unroll
    for (int r = 0; r < 4; ++r)
      sEx[(og * 16 + n16) * 16 + quad * 4 + r] = fin[r];
  }
  __syncthreads();
  if (xy == 0) {
    int o = oh * 32 + og * 16 + n16;
    float4 res;
    float* rp = (float*)&res;
#pragma unroll
    for (int r = 0; r < 4; ++r) {
      int m = quad * 4 + r;
      float ay = sEx[(og * 16 + n16) * 16 + m];
      rp[r] = atan2f(ay, fin[r]);
    }
    float* dst = out + (((size_t)(b * 64 + o) * 32 + h) * 32 + wt * 16 + quad * 4);
    *(float4*)dst = res;
  }
}

extern "C" void kernel_launch(void* const* d_in, const int* in_sizes, int n_in,
                              void* d_out, int out_size, void* d_ws, size_t ws_size,
                              hipStream_t stream) {
  const float* x = (const float*)d_in[0];
  const float* probe = (const float*)d_in[1];
  const float* outw = (const float*)d_in[2];
  char* Bg = (char*)d_ws;
  float* out = (float*)d_out;

  ring_prep_b<<<72, 256, 0, stream>>>(probe, outw, Bg);
  ring_mfma<<<512, 256, 0, stream>>>(x, Bg, out);
}

// Round 10
// 69.783 us; speedup vs baseline: 2.6432x; 1.0205x over previous
//
#include <hip/hip_runtime.h>
#include <math.h>

// Problem constants: B=4, CIN=32, COUT=64, H=W=32, K=3, pad=1

typedef _Float16 half8 __attribute__((ext_vector_type(8)));
typedef float floatx4 __attribute__((ext_vector_type(4)));

// ---------------- workspace layout ----------------
// B_f16: [var 2][tap 9][n 128][chunk p 16][16B]  = 576 KB (L2-resident)
//   n = xy*64 + o (xy: 0=cos-weights, 1=sin-weights); position p holds
//   k-chunk q = p ^ (n & 7); k = q*8 + j, c = k>>2, feat = k&3
//   var 0 = hi, var 1 = lo*2048
// NOTE (R9 failure): B-lo CANNOT be dropped — ay abs-err ~3e-3 flips the
// atan2 branch cut at the ~50 pixels with ay~0, ax<0 -> 2pi absmax.
#define B_TAP_STRIDE (128 * 256)      // 32768
#define B_VSTRIDE (9u * 128 * 256)    // 294912

__global__ __launch_bounds__(256) void ring_prep_b(
    const float* __restrict__ probe, const float* __restrict__ outw,
    char* __restrict__ Bg) {
  int i = blockIdx.x * 256 + threadIdx.x;   // 18432 threads = 72 blocks
  int p = i & 15;
  int n = (i >> 4) & 127;
  int tap = i >> 11;
  int qd = p ^ (n & 7);
  int o = n & 63;
  int xy = n >> 6;
  half8 hi, lo;
#pragma unroll
  for (int hf = 0; hf < 2; ++hf) {
    int c = qd * 2 + hf;
    int idx = (c * 64 + o) * 9 + tap;       // ((c*COUT + o)*3 + k)*3 + l
    float th = probe[idx];
    float wvv = outw[idx];
    float sth, cth, sw, cw;
    __sincosf(th, &sth, &cth);
    __sincosf(wvv, &sw, &cw);
    float c3 = cth * fmaf(4.0f * cth, cth, -3.0f);
    float s3 = sth * fmaf(-4.0f * sth, sth, 3.0f);
    float m = xy ? sw : cw;
    float v4[4] = {0.75f * m * cth, 0.75f * m * sth, 0.25f * m * c3,
                   0.25f * m * s3};
#pragma unroll
    for (int f = 0; f < 4; ++f) {
      _Float16 hv = (_Float16)v4[f];
      hi[hf * 4 + f] = hv;
      lo[hf * 4 + f] = (_Float16)((v4[f] - (float)hv) * 2048.0f);
    }
  }
  size_t off = (((size_t)tap * 128 + n) * 16 + p) * 16;
  *(half8*)(Bg + off) = hi;
  *(half8*)(Bg + off + B_VSTRIDE) = lo;
}

// Block: 16 px (row h, w = wt*16..+15) x 64 n ({oh*32..+31} u {64+oh*32..+31}).
// 4 waves; wave wv: xy = wv>>1, og = wv&1 -> one 16x16 n-frag, one 16-px m-frag.
// A-tile features (fp16 hi + lo*2048) computed in-block into swizzled LDS.
// sA layout: [var 2][r 3][colidx 18][p 16][16B]; chunk q = p ^ (colidx & 7).
// B (hi+lo) read directly from global/L2 with an explicit 2-stage register
// double-buffer: tap t+1's 8 fragments prefetched while tap t MFMAs.
__global__ __launch_bounds__(256, 2) void ring_mfma(
    const float* __restrict__ x, const char* __restrict__ Bg,
    float* __restrict__ out) {
  __shared__ __align__(16) char sA[27648];
  __shared__ float sEx[512];  // [og 2][n 16][m 16]

  int blk = blockIdx.x;  // ((b*32 + h)*2 + wt)*2 + oh
  int oh = blk & 1;
  int wt = (blk >> 1) & 1;
  int h = (blk >> 2) & 31;
  int b = blk >> 7;
  int tid = threadIdx.x;

  int lane = tid & 63;
  int wv = tid >> 6;
  int n16 = lane & 15;
  int quad = lane >> 4;
  int xy = wv >> 1;
  int og = wv & 1;

  // global n this lane's B column lives at; swizzle key n&7 == n16&7 since
  // xy*64, oh*32, og*16 are all 0 mod 8.
  int n_global = xy * 64 + oh * 32 + og * 16 + n16;
  const char* bRow = Bg + (size_t)n_global * 256;
  const char* bRowL = bRow + B_VSTRIDE;
  int bkey = n16 & 7;

  // ---- prefetch tap 0's B fragments (in flight across the A-setup) ----
  half8 BcH0, BcH1, BcH2, BcH3, BcL0, BcL1, BcL2, BcL3;
  {
    int p0 = ((0 * 4 + quad) ^ bkey) * 16;
    int p1 = ((1 * 4 + quad) ^ bkey) * 16;
    int p2 = ((2 * 4 + quad) ^ bkey) * 16;
    int p3 = ((3 * 4 + quad) ^ bkey) * 16;
    BcH0 = *(const half8*)(bRow + p0);
    BcH1 = *(const half8*)(bRow + p1);
    BcH2 = *(const half8*)(bRow + p2);
    BcH3 = *(const half8*)(bRow + p3);
    BcL0 = *(const half8*)(bRowL + p0);
    BcL1 = *(const half8*)(bRowL + p1);
    BcL2 = *(const half8*)(bRowL + p2);
    BcL3 = *(const half8*)(bRowL + p3);
  }

  // ---- compute A tile in-block: 864 hi/lo unit pairs ----
  for (int u = tid; u < 864; u += 256) {
    int r = u / 288;
    int t = u - r * 288;
    int colidx = t >> 4;
    int p = t & 15;
    int q = p ^ (colidx & 7);
    int hs = h + r - 1;
    int wsx = wt * 16 + colidx - 1;
    bool valid = ((unsigned)hs < 32u) && ((unsigned)wsx < 32u);
    half8 hi, lo;
#pragma unroll
    for (int hf = 0; hf < 2; ++hf) {
      int c = q * 2 + hf;
      float c1 = 1.0f, s1 = 0.0f;
      if (valid) {
        float pv = x[((b * 32 + c) * 32 + hs) * 32 + wsx];
        __sincosf(pv, &s1, &c1);
      }
      float c3 = c1 * fmaf(4.0f * c1, c1, -3.0f);
      float s3 = s1 * fmaf(-4.0f * s1, s1, 3.0f);
      float v4[4] = {c1, s1, c3, s3};
#pragma unroll
      for (int f = 0; f < 4; ++f) {
        _Float16 hv = (_Float16)v4[f];
        hi[hf * 4 + f] = hv;
        lo[hf * 4 + f] = (_Float16)((v4[f] - (float)hv) * 2048.0f);
      }
    }
    *(half8*)(sA + u * 16) = hi;            // var 0 section
    *(half8*)(sA + u * 16 + 13824) = lo;    // var 1 section (864*16)
  }

  floatx4 acc0 = {0.f, 0.f, 0.f, 0.f};   // Ah*Bh
  floatx4 acc1 = {0.f, 0.f, 0.f, 0.f};   // Al*Bh
  floatx4 acc2 = {0.f, 0.f, 0.f, 0.f};   // Ah*Bl

  __syncthreads();  // A tile visible; tap loop is barrier-free

#pragma unroll
  for (int tap = 0; tap < 9; ++tap) {
    // prefetch next tap's B (hi+lo) into the other buffer
    half8 BnH0, BnH1, BnH2, BnH3, BnL0, BnL1, BnL2, BnL3;
    if (tap < 8) {
      const char* bn = bRow + (size_t)(tap + 1) * B_TAP_STRIDE;
      const char* bnL = bn + B_VSTRIDE;
      int p0 = ((0 * 4 + quad) ^ bkey) * 16;
      int p1 = ((1 * 4 + quad) ^ bkey) * 16;
      int p2 = ((2 * 4 + quad) ^ bkey) * 16;
      int p3 = ((3 * 4 + quad) ^ bkey) * 16;
      BnH0 = *(const half8*)(bn + p0);
      BnH1 = *(const half8*)(bn + p1);
      BnH2 = *(const half8*)(bn + p2);
      BnH3 = *(const half8*)(bn + p3);
      BnL0 = *(const half8*)(bnL + p0);
      BnL1 = *(const half8*)(bnL + p1);
      BnL2 = *(const half8*)(bnL + p2);
      BnL3 = *(const half8*)(bnL + p3);
    }

    int dk = tap / 3;
    int l = tap - dk * 3;
    int colidx = n16 + l;  // m + l; m = lane&15 (pixel index)
    int akey = colidx & 7;
    const char* aH = sA + (dk * 18 + colidx) * 256;
    const char* aL = sA + ((3 + dk) * 18 + colidx) * 256;

#pragma unroll
    for (int ks = 0; ks < 4; ++ks) {
      int pa = ((ks * 4 + quad) ^ akey) * 16;
      half8 Ah = *(const half8*)(aH + pa);
      half8 Al = *(const half8*)(aL + pa);
      half8 Bh = (ks == 0) ? BcH0 : (ks == 1) ? BcH1 : (ks == 2) ? BcH2 : BcH3;
      half8 Bl = (ks == 0) ? BcL0 : (ks == 1) ? BcL1 : (ks == 2) ? BcL2 : BcL3;
      acc0 = __builtin_amdgcn_mfma_f32_16x16x32_f16(Ah, Bh, acc0, 0, 0, 0);
      acc1 = __builtin_amdgcn_mfma_f32_16x16x32_f16(Al, Bh, acc1, 0, 0, 0);
      acc2 = __builtin_amdgcn_mfma_f32_16x16x32_f16(Ah, Bl, acc2, 0, 0, 0);
    }
    BcH0 = BnH0; BcH1 = BnH1; BcH2 = BnH2; BcH3 = BnH3;
    BcL0 = BnL0; BcL1 = BnL1; BcL2 = BnL2; BcL3 = BnL3;
  }

  floatx4 fin = acc0 + (acc1 + acc2) * (1.0f / 2048.0f);

  // ---- epilogue: y-waves hand ay to x-waves; x-waves atan2 + store ----
  __syncthreads();
  if (xy == 1) {
#pragma unroll
    for (int r = 0; r < 4; ++r)
      sEx[(og * 16 + n16) * 16 + quad * 4 + r] = fin[r];
  }
  __syncthreads();
  if (xy == 0) {
    int o = oh * 32 + og * 16 + n16;
    float4 res;
    float* rp = (float*)&res;
#pragma unroll
    for (int r = 0; r < 4; ++r) {
      int m = quad * 4 + r;
      float ay = sEx[(og * 16 + n16) * 16 + m];
      rp[r] = atan2f(ay, fin[r]);
    }
    float* dst = out + (((size_t)(b * 64 + o) * 32 + h) * 32 + wt * 16 + quad * 4);
    *(float4*)dst = res;
  }
}

extern "C" void kernel_launch(void* const* d_in, const int* in_sizes, int n_in,
                              void* d_out, int out_size, void* d_ws, size_t ws_size,
                              hipStream_t stream) {
  const float* x = (const float*)d_in[0];
  const float* probe = (const float*)d_in[1];
  const float* outw = (const float*)d_in[2];
  char* Bg = (char*)d_ws;
  float* out = (float*)d_out;

  ring_prep_b<<<72, 256, 0, stream>>>(probe, outw, Bg);
  ring_mfma<<<512, 256, 0, stream>>>(x, Bg, out);
}